// Round 8
// baseline (286.827 us; speedup 1.0000x reference)
//
#include <hip/hip_runtime.h>
#include <hip/hip_fp16.h>
#include <math.h>

#define EMBED   128
#define NHEADS  8
#define NPOINTS 4
#define HD      16
#define HSP     51
#define WSP     102
#define NPIX    (HSP * WSP)   // 5202
#define NQ      10000
#define NLVL    50

// Zero-padded pixel-major maps: rows -1..52 (54), cols -1..103 (105).
// Valid source pixel (y,x) -> map slot (y+1, x+1); border slots zero, so OOB
// bilinear corners contribute exact +0 without masks.
#define PROW 54
#define PCOL 105
#define NSLOT (PROW * PCOL)        // 5670
#define ROWH  (PCOL * 32)          // value-map row stride in h4v units = 3360
#define GROW  (PCOL * NHEADS)      // gmap row stride in floats = 840

// 8-byte vector of 4 halves: one lane's 4-channel slot of a pixel record.
struct h4v { __half2 a; __half2 b; };

// ---------------------------------------------------------------------------
// Fused prep kernel.
//   blocks [0, 709)        : padded fp16 value map + padded fp32 g map
//                            (g[slot][h] = sum_{ch in h} vproj[ch]*u[ch],
//                             u = W_out @ W_proj computed in-block)
//   blocks [709, 709+1250) : offsets + attention, 8 queries/block
// The fp32 gmap keeps the logit/argmax path exact (round-4 lesson: fp16
// logits flip near-tied argmaxes; round-5 proved fp16 samples + fp32 gmap
// passes).
// ---------------------------------------------------------------------------
#define GRID_A ((NSLOT + 7) / 8)   // 709
#define GRID_B (NQ / 8)            // 1250

__global__ __launch_bounds__(256) void k_prep(
    const float* __restrict__ value,
    const float* __restrict__ Wv,
    const float* __restrict__ bv,
    const float* __restrict__ query,
    const float* __restrict__ Woff,
    const float* __restrict__ boff,
    const float* __restrict__ Wattn,
    const float* __restrict__ battn,
    const float* __restrict__ Wout,
    const float* __restrict__ Wproj,
    __half* __restrict__ vout,    // (NSLOT, 128) padded pixel-major fp16
    float* __restrict__ gout,     // (NSLOT, 8) padded fp32 logit map
    float* __restrict__ off_out,
    float* __restrict__ aw_out) {
    const int b = blockIdx.x;
    const int t = threadIdx.x;
    __shared__ float srow[8][EMBED];   // 4 KB: value rows or query rows
    __shared__ float4 u_s[32];

    if (b < GRID_A) {  // ---- padded value + g maps ----
        const int p    = t >> 5;       // slot index within block 0..7
        const int s    = t & 31;       // column group (4 cols each)
        const int slot = b * 8 + p;
        const int prow = slot / PCOL;
        const int pcol = slot - prow * PCOL;
        const bool inb   = slot < NSLOT;
        const bool valid = inb && prow >= 1 && prow <= HSP
                               && pcol >= 1 && pcol <= WSP;
        const int pix = (prow - 1) * WSP + (pcol - 1);
        if (valid)
            *(float4*)&srow[p][s * 4] =
                *(const float4*)(value + (size_t)pix * EMBED + s * 4);
        if (t < 32) {
            // u[t*4+j] = sum_d Wout[t*4+j][d] * Wproj[d]
            float4 u4 = {0.f, 0.f, 0.f, 0.f};
            const float* w0 = Wout + (size_t)(t * 4 + 0) * EMBED;
            const float* w1 = Wout + (size_t)(t * 4 + 1) * EMBED;
            const float* w2 = Wout + (size_t)(t * 4 + 2) * EMBED;
            const float* w3 = Wout + (size_t)(t * 4 + 3) * EMBED;
#pragma unroll 4
            for (int d = 0; d < EMBED; d += 4) {
                const float4 wp = *(const float4*)(Wproj + d);
                const float4 a = *(const float4*)(w0 + d);
                const float4 c = *(const float4*)(w1 + d);
                const float4 e = *(const float4*)(w2 + d);
                const float4 f = *(const float4*)(w3 + d);
                u4.x = fmaf(a.x, wp.x, u4.x); u4.x = fmaf(a.y, wp.y, u4.x);
                u4.x = fmaf(a.z, wp.z, u4.x); u4.x = fmaf(a.w, wp.w, u4.x);
                u4.y = fmaf(c.x, wp.x, u4.y); u4.y = fmaf(c.y, wp.y, u4.y);
                u4.y = fmaf(c.z, wp.z, u4.y); u4.y = fmaf(c.w, wp.w, u4.y);
                u4.z = fmaf(e.x, wp.x, u4.z); u4.z = fmaf(e.y, wp.y, u4.z);
                u4.z = fmaf(e.z, wp.z, u4.z); u4.z = fmaf(e.w, wp.w, u4.z);
                u4.w = fmaf(f.x, wp.x, u4.w); u4.w = fmaf(f.y, wp.y, u4.w);
                u4.w = fmaf(f.z, wp.z, u4.w); u4.w = fmaf(f.w, wp.w, u4.w);
            }
            u_s[t] = u4;
        }
        __syncthreads();
        float4 acc = {0.f, 0.f, 0.f, 0.f};
        if (valid) {
            acc = *(const float4*)(bv + s * 4);
            const float* vr = srow[p];
            const float* wp = Wv + s * 4;
#pragma unroll 8
            for (int k = 0; k < EMBED; ++k) {
                const float qv = vr[k];
                const float4 w4 = *(const float4*)(wp + (size_t)k * EMBED);
                acc.x = fmaf(qv, w4.x, acc.x);
                acc.y = fmaf(qv, w4.y, acc.y);
                acc.z = fmaf(qv, w4.z, acc.z);
                acc.w = fmaf(qv, w4.w, acc.w);
            }
        }
        // per-head logit partial from the PRE-ROUNDING fp32 acc (0 on border)
        const float4 u4 = u_s[s];
        float gp = acc.x * u4.x;
        gp = fmaf(acc.y, u4.y, gp);
        gp = fmaf(acc.z, u4.z, gp);
        gp = fmaf(acc.w, u4.w, gp);
        gp += __shfl_xor(gp, 1, 64);
        gp += __shfl_xor(gp, 2, 64);   // sum over the 4 lanes of this head
        if (inb) {
            h4v hv;
            hv.a = __floats2half2_rn(acc.x, acc.y);
            hv.b = __floats2half2_rn(acc.z, acc.w);
            *(h4v*)(vout + (size_t)slot * EMBED + s * 4) = hv;
            if ((s & 3) == 0)
                gout[(size_t)slot * NHEADS + (s >> 2)] = gp;
        }
    } else if (b < GRID_A + GRID_B) {  // ---- offsets + attention ----
        const int qi = t >> 5;         // query slot 0..7
        const int s  = t & 31;
        const int q  = (b - GRID_A) * 8 + qi;
        *(float4*)&srow[qi][s * 4] =
            *(const float4*)(query + (size_t)q * EMBED + s * 4);
        __syncthreads();
        if (s < 24) {                  // lanes 0-15: offsets, 16-23: attn
            const float* vr = srow[qi];
            const float* wp;
            int wstride;
            float4 acc;
            if (s < 16) {
                wp = Woff + s * 4; wstride = 64;
                acc = *(const float4*)(boff + s * 4);
            } else {
                wp = Wattn + (s - 16) * 4; wstride = 32;
                acc = *(const float4*)(battn + (s - 16) * 4);
            }
#pragma unroll 8
            for (int k = 0; k < EMBED; ++k) {
                const float qv = vr[k];
                const float4 w4 = *(const float4*)(wp + (size_t)k * wstride);
                acc.x = fmaf(qv, w4.x, acc.x);
                acc.y = fmaf(qv, w4.y, acc.y);
                acc.z = fmaf(qv, w4.z, acc.z);
                acc.w = fmaf(qv, w4.w, acc.w);
            }
            if (s < 16) {
                *(float4*)(off_out + (size_t)q * 64 + s * 4) = acc;
            } else {
                const float mx = fmaxf(fmaxf(acc.x, acc.y), fmaxf(acc.z, acc.w));
                const float e0 = __expf(acc.x - mx), e1 = __expf(acc.y - mx);
                const float e2 = __expf(acc.z - mx), e3 = __expf(acc.w - mx);
                const float inv = 1.f / (e0 + e1 + e2 + e3);
                float4 r;
                r.x = e0 * inv; r.y = e1 * inv; r.z = e2 * inv; r.w = e3 * inv;
                *(float4*)(aw_out + (size_t)q * 32 + (s - 16) * 4) = r;
            }
        }
    }
}

// ---------------------------------------------------------------------------
// Main kernel. Round-10 = round-7's fused loop + padded lean addressing,
// with the TCP-return-bandwidth fix (the measured ~104 us floor):
//  * vflat is fp16 -> corner loads are 8 B dwordx2 (half the TCP bytes);
//    consume via fmaf(w, (float)half, s) which the gfx9+ backend folds to
//    v_fma_mix_f32 (no separate cvt ops — round-5's regression cause).
//  * logits from the padded fp32 gmap IN the loop (round-5's exact per-lane
//    formula — argmax-proven), 4 scalar loads per lane-iter; the u-dot and
//    uvec are gone from the loop.
// NOTE: the half-merge MUST also merge m (m = fmaxf(m, mo)) — the cross-wave
// merge consumes m as the comparison key (round-3 bug).
// ---------------------------------------------------------------------------
__global__ __launch_bounds__(256, 4) void k_main(
    const float* __restrict__ query,
    const float* __restrict__ refp,   // (NLVL, NQ, 2)
    const float* __restrict__ voff,   // (NQ, 8, 4, 2)
    const float* __restrict__ vaw,    // (NQ, 8, 4)
    const __half* __restrict__ vflat, // (NSLOT, 128) padded pixel-major fp16
    const float* __restrict__ gmap,   // (NSLOT, 8) padded fp32 logit map
    const float* __restrict__ Wout,   // (128, 128)
    const float* __restrict__ bout,   // (128)
    float* __restrict__ out0,         // (NQ, 128)
    float* __restrict__ out1) {       // (NQ) argmax level, as float
    const int t = threadIdx.x;
    const int qslot = t >> 7;         // 0..1
    const int w2 = (t >> 6) & 1;      // wave index within query
    const int half = (t >> 5) & 1;
    const int sub = t & 31;
    const int h  = sub >> 2;
    const int c4 = sub & 3;
    const int q = blockIdx.x * 2 + qslot;

    __shared__ float  s_rpy[2][NLVL];
    __shared__ float4 s_acc[2][32];
    __shared__ float  s_z[2], s_m[2];
    __shared__ int    s_b[2];

    // cooperative preload of ref.y for this block's 2 queries
    if (t < 2 * NLVL) {
        const int ql = t / NLVL, l = t - ql * NLVL;
        const int qq = blockIdx.x * 2 + ql;
        s_rpy[ql][l] = refp[((size_t)l * NQ + qq) * 2 + 1];
    }

    const float4* offp = (const float4*)(voff + (size_t)q * 64 + h * 8);
    const float4 o01 = offp[0];       // p0.x p0.y p1.x p1.y
    const float4 o23 = offp[1];
    const float4 awv4 = *(const float4*)(vaw + (size_t)q * 32 + h * 4);
    const float rpx = refp[(size_t)q * 2];   // col is level-invariant
    const h4v* vflat_h4 = (const h4v*)vflat;  // uniform base (SGPR pair)

    const float offx[4] = {o01.x, o01.z, o23.x, o23.z};
    const float offy[4] = {o01.y, o01.w, o23.y, o23.w};
    const float awv[4]  = {awv4.x, awv4.y, awv4.z, awv4.w};

    // level-independent x-axis state per point; xa[p] pre-folds the +1
    // row/col pad shifts and the lane slot (sub).
    float wx0[NPOINTS], wx1[NPOINTS], oyc[NPOINTS];
    int xa[NPOINTS];
#pragma unroll
    for (int p = 0; p < NPOINTS; ++p) {
        const float px = fmaf(rpx, (float)WSP, offx[p]) - 0.5f;
        const float pxc = __builtin_amdgcn_fmed3f(px, -1.f, (float)WSP);
        const float fx = floorf(pxc);
        const float dx = pxc - fx;
        const int x0 = (int)fx;
        const float a = awv[p];
        wx0[p] = a * (1.f - dx);
        wx1[p] = a * dx;
        xa[p] = (x0 + 1) * 32 + ROWH + sub;
        oyc[p] = offy[p] - 0.5f;
    }

    // this lane's own (h, p=c4) point: scalar x-state for the fp32 g map
    const float offx_c = (c4 == 0) ? o01.x : (c4 == 1) ? o01.z : (c4 == 2) ? o23.x : o23.z;
    const float offy_c = (c4 == 0) ? o01.y : (c4 == 1) ? o01.w : (c4 == 2) ? o23.y : o23.w;
    const float a_c    = (c4 == 0) ? awv4.x : (c4 == 1) ? awv4.y : (c4 == 2) ? awv4.z : awv4.w;
    const float pxc = __builtin_amdgcn_fmed3f(
        fmaf(rpx, (float)WSP, offx_c) - 0.5f, -1.f, (float)WSP);
    const float fxc = floorf(pxc);
    const float dxc = pxc - fxc;
    const float gwx0 = a_c * (1.f - dxc);
    const float gwx1 = a_c * dxc;
    const int gxa = ((int)fxc + 1) * NHEADS + h + GROW;   // pad shifts folded
    const float oyc_c = offy_c - 0.5f;

    __syncthreads();

    float4 acc = {0.f, 0.f, 0.f, 0.f};
    float Z = 0.f, m = -1e30f;
    int best = 0;

#pragma unroll 1
    for (int i = 0; i < 13; ++i) {
        if (4 * i + (w2 << 1) >= NLVL) break;   // wave-uniform (depends on w2 only)
        const int l = 4 * i + (w2 << 1) + half;
        const float rpy = s_rpy[qslot][l];

        // ---- this lane's logit gathers (fp32 g map, padded) ----
        const float pyc = __builtin_amdgcn_fmed3f(
            fmaf(rpy, (float)HSP, oyc_c), -1.f, (float)HSP);
        const float fyc = floorf(pyc);
        const float dyc = pyc - fyc;
        const int gi0 = (int)fyc * GROW + gxa;
        const float g00 = gmap[gi0];
        const float g01 = gmap[gi0 + NHEADS];
        const float g10 = gmap[gi0 + GROW];
        const float g11 = gmap[gi0 + GROW + NHEADS];

        // ---- stage: issue all 16 corner loads (8 B each), then consume ----
        h4v v00[NPOINTS], v01[NPOINTS], v10[NPOINTS], v11[NPOINTS];
        float w00[NPOINTS], w01[NPOINTS], w10[NPOINTS], w11[NPOINTS];
#pragma unroll
        for (int p = 0; p < NPOINTS; ++p) {
            const float py = fmaf(rpy, (float)HSP, oyc[p]);
            const float pyc2 = __builtin_amdgcn_fmed3f(py, -1.f, (float)HSP);
            const float fy = floorf(pyc2);
            const float dy = pyc2 - fy;
            const int y0 = (int)fy;
            const int i0 = y0 * ROWH + xa[p];   // map row y0+1 (pad folded)
            const int i1 = i0 + ROWH;           // map row y0+2
            const float t0 = 1.f - dy;
            v00[p] = vflat_h4[i0];
            v01[p] = vflat_h4[i0 + 32];         // +256 B -> imm offset fold
            v10[p] = vflat_h4[i1];
            v11[p] = vflat_h4[i1 + 32];
            w00[p] = wx0[p] * t0;
            w01[p] = wx1[p] * t0;
            w10[p] = wx0[p] * dy;
            w11[p] = wx1[p] * dy;
        }
        float4 s = {0.f, 0.f, 0.f, 0.f};
#pragma unroll
        for (int p = 0; p < NPOINTS; ++p) {
            s.x = fmaf(w00[p], __half2float(__low2half(v00[p].a)), s.x);
            s.y = fmaf(w00[p], __half2float(__high2half(v00[p].a)), s.y);
            s.z = fmaf(w00[p], __half2float(__low2half(v00[p].b)), s.z);
            s.w = fmaf(w00[p], __half2float(__high2half(v00[p].b)), s.w);
            s.x = fmaf(w01[p], __half2float(__low2half(v01[p].a)), s.x);
            s.y = fmaf(w01[p], __half2float(__high2half(v01[p].a)), s.y);
            s.z = fmaf(w01[p], __half2float(__low2half(v01[p].b)), s.z);
            s.w = fmaf(w01[p], __half2float(__high2half(v01[p].b)), s.w);
            s.x = fmaf(w10[p], __half2float(__low2half(v10[p].a)), s.x);
            s.y = fmaf(w10[p], __half2float(__high2half(v10[p].a)), s.y);
            s.z = fmaf(w10[p], __half2float(__low2half(v10[p].b)), s.z);
            s.w = fmaf(w10[p], __half2float(__high2half(v10[p].b)), s.w);
            s.x = fmaf(w11[p], __half2float(__low2half(v11[p].a)), s.x);
            s.y = fmaf(w11[p], __half2float(__high2half(v11[p].a)), s.y);
            s.z = fmaf(w11[p], __half2float(__low2half(v11[p].b)), s.z);
            s.w = fmaf(w11[p], __half2float(__high2half(v11[p].b)), s.w);
        }
        // logit from the fp32 g map (round-5 formula), reduced over 32 lanes
        float row0 = gwx0 * g00; row0 = fmaf(gwx1, g01, row0);
        float row1 = gwx0 * g10; row1 = fmaf(gwx1, g11, row1);
        float part = (1.f - dyc) * row0; part = fmaf(dyc, row1, part);
#pragma unroll
        for (int d = 1; d < 32; d <<= 1)
            part += __shfl_xor(part, d, 64);
        const float e = __expf(part);
        Z += e;
        acc.x = fmaf(e, s.x, acc.x);
        acc.y = fmaf(e, s.y, acc.y);
        acc.z = fmaf(e, s.z, acc.z);
        acc.w = fmaf(e, s.w, acc.w);
        best = (part > m) ? l : best;   // strict > : first occurrence wins
        m = fmaxf(part, m);
    }

    // merge the two halves of this wave (exact: plain sums, no rescale)
    {
        const float mo = __shfl_xor(m, 32, 64);
        const int   bo = __shfl_xor(best, 32, 64);
        const float Zo = __shfl_xor(Z, 32, 64);
        const float ax = __shfl_xor(acc.x, 32, 64);
        const float ay = __shfl_xor(acc.y, 32, 64);
        const float az = __shfl_xor(acc.z, 32, 64);
        const float aw_ = __shfl_xor(acc.w, 32, 64);
        const bool takeOther = (mo > m) || (mo == m && bo < best);
        best = takeOther ? bo : best;
        m = fmaxf(m, mo);               // <- merge the key too (round-3 fix)
        Z += Zo;
        acc.x += ax; acc.y += ay; acc.z += az; acc.w += aw_;
    }

    // wave 1 publishes its partials; wave 0 merges and finishes
    if (w2 == 1) {
        if (half == 0) s_acc[qslot][sub] = acc;
        if ((t & 63) == 0) { s_z[qslot] = Z; s_m[qslot] = m; s_b[qslot] = best; }
    }
    __syncthreads();

    if (w2 == 0) {
        const float4 ao = s_acc[qslot][sub];
        const float Zo = s_z[qslot];
        const float mo = s_m[qslot];
        const int   bo = s_b[qslot];
        const bool takeOther = (mo > m) || (mo == m && bo < best);
        best = takeOther ? bo : best;
        Z += Zo;
        acc.x += ao.x; acc.y += ao.y; acc.z += ao.z; acc.w += ao.w;

        const float inv = 1.f / Z;
        if (half == 0) {
            float4 sv;
            sv.x = acc.x * inv; sv.y = acc.y * inv;
            sv.z = acc.z * inv; sv.w = acc.w * inv;
            s_acc[qslot][sub] = sv;       // channel-group index == sub
            if (sub == 0) out1[q] = (float)best;
        }
        // same-wave DS ordering makes the write visible to both halves below

        // final: out[dp] = sum_c s[c]*Wout[c][dp] + bout[dp] + 2*query[q][dp]
        // split-K across the two halves: half0 sums cg 0..15, half1 cg 16..31
        const int dpb = sub * 4;
        float4 r = {0.f, 0.f, 0.f, 0.f};
        if (half == 0) {
            const float4 b4 = *(const float4*)(bout + dpb);
            const float4 q4 = *(const float4*)(query + (size_t)q * EMBED + dpb);
            r.x = fmaf(2.f, q4.x, b4.x);
            r.y = fmaf(2.f, q4.y, b4.y);
            r.z = fmaf(2.f, q4.z, b4.z);
            r.w = fmaf(2.f, q4.w, b4.w);
        }
        const float4* srow = s_acc[qslot];
        const int cg0 = half * 16;
#pragma unroll 4
        for (int cg = cg0; cg < cg0 + 16; ++cg) {
            const float4 s4 = srow[cg];
            const float4 w0 = *(const float4*)(Wout + (size_t)(cg * 4 + 0) * EMBED + dpb);
            const float4 w1 = *(const float4*)(Wout + (size_t)(cg * 4 + 1) * EMBED + dpb);
            const float4 w2v = *(const float4*)(Wout + (size_t)(cg * 4 + 2) * EMBED + dpb);
            const float4 w3 = *(const float4*)(Wout + (size_t)(cg * 4 + 3) * EMBED + dpb);
            r.x = fmaf(s4.x, w0.x, r.x); r.y = fmaf(s4.x, w0.y, r.y);
            r.z = fmaf(s4.x, w0.z, r.z); r.w = fmaf(s4.x, w0.w, r.w);
            r.x = fmaf(s4.y, w1.x, r.x); r.y = fmaf(s4.y, w1.y, r.y);
            r.z = fmaf(s4.y, w1.z, r.z); r.w = fmaf(s4.y, w1.w, r.w);
            r.x = fmaf(s4.z, w2v.x, r.x); r.y = fmaf(s4.z, w2v.y, r.y);
            r.z = fmaf(s4.z, w2v.z, r.z); r.w = fmaf(s4.z, w2v.w, r.w);
            r.x = fmaf(s4.w, w3.x, r.x); r.y = fmaf(s4.w, w3.y, r.y);
            r.z = fmaf(s4.w, w3.z, r.z); r.w = fmaf(s4.w, w3.w, r.w);
        }
        // combine the two half-sums and store from half 0
        {
            const float rx = __shfl_xor(r.x, 32, 64);
            const float ry = __shfl_xor(r.y, 32, 64);
            const float rz = __shfl_xor(r.z, 32, 64);
            const float rw = __shfl_xor(r.w, 32, 64);
            r.x += rx; r.y += ry; r.z += rz; r.w += rw;
        }
        if (half == 0)
            *(float4*)(out0 + (size_t)q * EMBED + dpb) = r;
    }
}

// ---------------------------------------------------------------------------
extern "C" void kernel_launch(void* const* d_in, const int* in_sizes, int n_in,
                              void* d_out, int out_size, void* d_ws, size_t ws_size,
                              hipStream_t stream) {
    const float* query = (const float*)d_in[0];
    const float* value = (const float*)d_in[1];
    const float* refp  = (const float*)d_in[2];
    const float* Woff  = (const float*)d_in[3];
    const float* boff  = (const float*)d_in[4];
    const float* Wattn = (const float*)d_in[5];
    const float* battn = (const float*)d_in[6];
    const float* Wval  = (const float*)d_in[7];
    const float* bval  = (const float*)d_in[8];
    const float* Wout  = (const float*)d_in[9];
    const float* bout  = (const float*)d_in[10];
    const float* Wproj = (const float*)d_in[11];
    // d_in[12] = b_proj: level-constant -> cancels in softmax/argmax, unused.

    float* ws = (float*)d_ws;
    __half* ws_v = (__half*)ws;                           // NSLOT*128 halves
    float* ws_g   = ws + (size_t)NSLOT * EMBED / 2;       // NSLOT*8 fp32
    float* ws_off = ws_g + (size_t)NSLOT * NHEADS;        // NQ*64
    float* ws_aw  = ws_off + (size_t)NQ * 64;             // NQ*32

    float* out0 = (float*)d_out;
    float* out1 = out0 + (size_t)NQ * EMBED;

    hipLaunchKernelGGL(k_prep, dim3(GRID_A + GRID_B), dim3(256), 0, stream,
                       value, Wval, bval, query, Woff, boff, Wattn, battn,
                       Wout, Wproj, ws_v, ws_g, ws_off, ws_aw);
    hipLaunchKernelGGL(k_main, dim3(NQ / 2), dim3(256), 0, stream,
                       query, refp, ws_off, ws_aw, ws_v, ws_g, Wout, bout,
                       out0, out1);
}

// Round 9
// 256.976 us; speedup vs baseline: 1.1162x; 1.1162x over previous
//
#include <hip/hip_runtime.h>
#include <math.h>

#define EMBED   128
#define NHEADS  8
#define NPOINTS 4
#define HD      16
#define HSP     51
#define WSP     102
#define NPIX    (HSP * WSP)   // 5202
#define NQ      10000
#define NLVL    50

// Zero-padded pixel-major value map: rows -1..52 (54), cols -1..103 (105).
// Valid source pixel (y,x) lives at map slot (y+1, x+1). Border slots are
// zero-filled, so out-of-range bilinear corners contribute exact +0 without
// any validity masks in the inner loop.
#define PROW 54
#define PCOL 105
#define NSLOT (PROW * PCOL)        // 5670
#define ROWQ  (PCOL * 32)          // row stride in float4 units = 3360

// ---------------------------------------------------------------------------
// Fused prep kernel (identical to round 7 — verified).
//   blocks [0, 709)        : padded value map (8 map-slots/block; border -> 0)
//   blocks [709, 709+1250) : offsets + attention, 8 queries/block
//   last block             : u = W_out @ W_proj
// ---------------------------------------------------------------------------
#define GRID_A ((NSLOT + 7) / 8)   // 709
#define GRID_B (NQ / 8)            // 1250

__global__ __launch_bounds__(256) void k_prep(
    const float* __restrict__ value,
    const float* __restrict__ Wv,
    const float* __restrict__ bv,
    const float* __restrict__ query,
    const float* __restrict__ Woff,
    const float* __restrict__ boff,
    const float* __restrict__ Wattn,
    const float* __restrict__ battn,
    const float* __restrict__ Wout,
    const float* __restrict__ Wproj,
    float* __restrict__ vout,     // (PROW*PCOL, 128) padded pixel-major
    float* __restrict__ off_out,
    float* __restrict__ aw_out,
    float* __restrict__ u_out) {
    const int b = blockIdx.x;
    const int t = threadIdx.x;
    __shared__ float srow[8][EMBED];   // 4 KB: value rows or query rows

    if (b < GRID_A) {  // ---- padded value map ----
        const int p    = t >> 5;       // slot index within block 0..7
        const int s    = t & 31;       // column group (4 cols each)
        const int slot = b * 8 + p;
        const int prow = slot / PCOL;
        const int pcol = slot - prow * PCOL;
        const bool inb   = slot < NSLOT;
        const bool valid = inb && prow >= 1 && prow <= HSP
                               && pcol >= 1 && pcol <= WSP;
        const int pix = (prow - 1) * WSP + (pcol - 1);
        if (valid)
            *(float4*)&srow[p][s * 4] =
                *(const float4*)(value + (size_t)pix * EMBED + s * 4);
        __syncthreads();
        float4 acc = {0.f, 0.f, 0.f, 0.f};
        if (valid) {
            acc = *(const float4*)(bv + s * 4);
            const float* vr = srow[p];
            const float* wp = Wv + s * 4;
#pragma unroll 8
            for (int k = 0; k < EMBED; ++k) {
                const float qv = vr[k];
                const float4 w4 = *(const float4*)(wp + (size_t)k * EMBED);
                acc.x = fmaf(qv, w4.x, acc.x);
                acc.y = fmaf(qv, w4.y, acc.y);
                acc.z = fmaf(qv, w4.z, acc.z);
                acc.w = fmaf(qv, w4.w, acc.w);
            }
        }
        if (inb)
            *(float4*)(vout + (size_t)slot * EMBED + s * 4) = acc;
    } else if (b < GRID_A + GRID_B) {  // ---- offsets + attention ----
        const int qi = t >> 5;         // query slot 0..7
        const int s  = t & 31;
        const int q  = (b - GRID_A) * 8 + qi;
        *(float4*)&srow[qi][s * 4] =
            *(const float4*)(query + (size_t)q * EMBED + s * 4);
        __syncthreads();
        if (s < 24) {                  // lanes 0-15: offsets, 16-23: attn
            const float* vr = srow[qi];
            const float* wp;
            int wstride;
            float4 acc;
            if (s < 16) {
                wp = Woff + s * 4; wstride = 64;
                acc = *(const float4*)(boff + s * 4);
            } else {
                wp = Wattn + (s - 16) * 4; wstride = 32;
                acc = *(const float4*)(battn + (s - 16) * 4);
            }
#pragma unroll 8
            for (int k = 0; k < EMBED; ++k) {
                const float qv = vr[k];
                const float4 w4 = *(const float4*)(wp + (size_t)k * wstride);
                acc.x = fmaf(qv, w4.x, acc.x);
                acc.y = fmaf(qv, w4.y, acc.y);
                acc.z = fmaf(qv, w4.z, acc.z);
                acc.w = fmaf(qv, w4.w, acc.w);
            }
            if (s < 16) {
                *(float4*)(off_out + (size_t)q * 64 + s * 4) = acc;
            } else {
                const float mx = fmaxf(fmaxf(acc.x, acc.y), fmaxf(acc.z, acc.w));
                const float e0 = __expf(acc.x - mx), e1 = __expf(acc.y - mx);
                const float e2 = __expf(acc.z - mx), e3 = __expf(acc.w - mx);
                const float inv = 1.f / (e0 + e1 + e2 + e3);
                float4 r;
                r.x = e0 * inv; r.y = e1 * inv; r.z = e2 * inv; r.w = e3 * inv;
                *(float4*)(aw_out + (size_t)q * 32 + (s - 16) * 4) = r;
            }
        }
    } else {  // ---- u = W_out @ W_proj (1 block) ----
        if (t < EMBED) {
            float acc = 0.f;
#pragma unroll 8
            for (int d = 0; d < EMBED; ++d)
                acc = fmaf(Wout[(size_t)t * EMBED + d], Wproj[d], acc);
            u_out[t] = acc;
        }
    }
}

// ---------------------------------------------------------------------------
// Main kernel. Round-11 = round-7 EXACTLY (best verified: 158 us) with the
// main loop manually unrolled by 2. Rationale: with unroll 1, iteration i+1's
// 16 corner loads cannot issue until iteration i's serial tail (5-shuffle
// reduce -> exp -> acc) retires — the compiler can't reorder across the loop
// back-edge (R7's VGPR=32 proves nothing was staged across it). Unrolling
// exposes the independence; the scheduler hoists body-2's loads under
// body-1's tail. acc/Z/m/best updates stay in original iteration order ->
// outputs bitwise identical to round 7.
// Trip counts preserved: pairs (0,1)..(10,11) for both waves, then body(12)
// for w2==0 only (the old wave-uniform break at 4*12+2 >= 50).
// NOTE: the half-merge MUST also merge m (m = fmaxf(m, mo)) — the cross-wave
// merge consumes m as the comparison key (round-3 bug).
// ---------------------------------------------------------------------------
__global__ __launch_bounds__(256, 4) void k_main(
    const float* __restrict__ query,
    const float* __restrict__ refp,   // (NLVL, NQ, 2)
    const float* __restrict__ voff,   // (NQ, 8, 4, 2)
    const float* __restrict__ vaw,    // (NQ, 8, 4)
    const float* __restrict__ vflat,  // (PROW*PCOL, 128) padded pixel-major
    const float* __restrict__ uvec,   // (128)
    const float* __restrict__ Wout,   // (128, 128)
    const float* __restrict__ bout,   // (128)
    float* __restrict__ out0,         // (NQ, 128)
    float* __restrict__ out1) {       // (NQ) argmax level, as float
    const int t = threadIdx.x;
    const int qslot = t >> 7;         // 0..1
    const int w2 = (t >> 6) & 1;      // wave index within query
    const int half = (t >> 5) & 1;
    const int sub = t & 31;
    const int h  = sub >> 2;
    const int c4 = sub & 3;
    const int q = blockIdx.x * 2 + qslot;

    __shared__ float  s_rpy[2][NLVL];
    __shared__ float4 s_acc[2][32];
    __shared__ float  s_z[2], s_m[2];
    __shared__ int    s_b[2];

    // cooperative preload of ref.y for this block's 2 queries
    if (t < 2 * NLVL) {
        const int ql = t / NLVL, l = t - ql * NLVL;
        const int qq = blockIdx.x * 2 + ql;
        s_rpy[ql][l] = refp[((size_t)l * NQ + qq) * 2 + 1];
    }

    const float4* offp = (const float4*)(voff + (size_t)q * 64 + h * 8);
    const float4 o01 = offp[0];       // p0.x p0.y p1.x p1.y
    const float4 o23 = offp[1];
    const float4 awv4 = *(const float4*)(vaw + (size_t)q * 32 + h * 4);
    const float4 u4 = *(const float4*)(uvec + h * 16 + c4 * 4);
    const float rpx = refp[(size_t)q * 2];   // col is level-invariant
    const float4* vflat4 = (const float4*)vflat;   // UNIFORM base (SGPR pair)

    const float offx[4] = {o01.x, o01.z, o23.x, o23.z};
    const float offy[4] = {o01.y, o01.w, o23.y, o23.w};
    const float awv[4]  = {awv4.x, awv4.y, awv4.z, awv4.w};

    // level-independent x-axis state per point. xa[p] pre-folds:
    //   (x0+1)*32  (col pad shift), +ROWQ (row pad shift), +sub (lane slot)
    float wx0[NPOINTS], wx1[NPOINTS], oyc[NPOINTS];
    int xa[NPOINTS];
#pragma unroll
    for (int p = 0; p < NPOINTS; ++p) {
        const float px = fmaf(rpx, (float)WSP, offx[p]) - 0.5f;
        const float pxc = __builtin_amdgcn_fmed3f(px, -1.f, (float)WSP);
        const float fx = floorf(pxc);
        const float dx = pxc - fx;
        const int x0 = (int)fx;
        const float a = awv[p];
        wx0[p] = a * (1.f - dx);
        wx1[p] = a * dx;
        xa[p] = (x0 + 1) * 32 + ROWQ + sub;
        oyc[p] = offy[p] - 0.5f;
    }

    __syncthreads();

    float4 acc = {0.f, 0.f, 0.f, 0.f};
    float Z = 0.f, m = -1e30f;
    int best = 0;

    // one level for this half: gather + logit + online-softmax update
#define LEVEL_BODY(ii)                                                        \
    {                                                                         \
        const int l = 4 * (ii) + (w2 << 1) + half;                            \
        const float rpy = s_rpy[qslot][l];                                    \
        float4 v00[NPOINTS], v01[NPOINTS], v10[NPOINTS], v11[NPOINTS];        \
        float w00[NPOINTS], w01[NPOINTS], w10[NPOINTS], w11[NPOINTS];         \
        _Pragma("unroll")                                                     \
        for (int p = 0; p < NPOINTS; ++p) {                                   \
            const float py = fmaf(rpy, (float)HSP, oyc[p]);                   \
            const float pyc = __builtin_amdgcn_fmed3f(py, -1.f, (float)HSP);  \
            const float fy = floorf(pyc);                                     \
            const float dy = pyc - fy;                                        \
            const int y0 = (int)fy;                                           \
            const int i0 = y0 * ROWQ + xa[p];                                 \
            const int i1 = i0 + ROWQ;                                         \
            const float t0 = 1.f - dy;                                        \
            v00[p] = vflat4[i0];                                              \
            v01[p] = vflat4[i0 + 32];                                         \
            v10[p] = vflat4[i1];                                              \
            v11[p] = vflat4[i1 + 32];                                         \
            w00[p] = wx0[p] * t0;                                             \
            w01[p] = wx1[p] * t0;                                             \
            w10[p] = wx0[p] * dy;                                             \
            w11[p] = wx1[p] * dy;                                             \
        }                                                                     \
        float4 s = {0.f, 0.f, 0.f, 0.f};                                      \
        _Pragma("unroll")                                                     \
        for (int p = 0; p < NPOINTS; ++p) {                                   \
            s.x = fmaf(w00[p], v00[p].x, s.x); s.y = fmaf(w00[p], v00[p].y, s.y); \
            s.z = fmaf(w00[p], v00[p].z, s.z); s.w = fmaf(w00[p], v00[p].w, s.w); \
            s.x = fmaf(w01[p], v01[p].x, s.x); s.y = fmaf(w01[p], v01[p].y, s.y); \
            s.z = fmaf(w01[p], v01[p].z, s.z); s.w = fmaf(w01[p], v01[p].w, s.w); \
            s.x = fmaf(w10[p], v10[p].x, s.x); s.y = fmaf(w10[p], v10[p].y, s.y); \
            s.z = fmaf(w10[p], v10[p].z, s.z); s.w = fmaf(w10[p], v10[p].w, s.w); \
            s.x = fmaf(w11[p], v11[p].x, s.x); s.y = fmaf(w11[p], v11[p].y, s.y); \
            s.z = fmaf(w11[p], v11[p].z, s.z); s.w = fmaf(w11[p], v11[p].w, s.w); \
        }                                                                     \
        float part = s.x * u4.x;                                              \
        part = fmaf(s.y, u4.y, part);                                         \
        part = fmaf(s.z, u4.z, part);                                         \
        part = fmaf(s.w, u4.w, part);                                         \
        _Pragma("unroll")                                                     \
        for (int d = 1; d < 32; d <<= 1)                                      \
            part += __shfl_xor(part, d, 64);                                  \
        const float e = __expf(part);                                         \
        Z += e;                                                               \
        acc.x = fmaf(e, s.x, acc.x);                                          \
        acc.y = fmaf(e, s.y, acc.y);                                          \
        acc.z = fmaf(e, s.z, acc.z);                                          \
        acc.w = fmaf(e, s.w, acc.w);                                          \
        best = (part > m) ? l : best;                                         \
        m = fmaxf(part, m);                                                   \
    }

#pragma unroll 1
    for (int i = 0; i < 12; i += 2) {
        LEVEL_BODY(i)
        LEVEL_BODY(i + 1)
    }
    if (w2 == 0)
        LEVEL_BODY(12)
#undef LEVEL_BODY

    // merge the two halves of this wave (exact: plain sums, no rescale)
    {
        const float mo = __shfl_xor(m, 32, 64);
        const int   bo = __shfl_xor(best, 32, 64);
        const float Zo = __shfl_xor(Z, 32, 64);
        const float ax = __shfl_xor(acc.x, 32, 64);
        const float ay = __shfl_xor(acc.y, 32, 64);
        const float az = __shfl_xor(acc.z, 32, 64);
        const float aw_ = __shfl_xor(acc.w, 32, 64);
        const bool takeOther = (mo > m) || (mo == m && bo < best);
        best = takeOther ? bo : best;
        m = fmaxf(m, mo);               // <- merge the key too (round-3 fix)
        Z += Zo;
        acc.x += ax; acc.y += ay; acc.z += az; acc.w += aw_;
    }

    // wave 1 publishes its partials; wave 0 merges and finishes
    if (w2 == 1) {
        if (half == 0) s_acc[qslot][sub] = acc;
        if ((t & 63) == 0) { s_z[qslot] = Z; s_m[qslot] = m; s_b[qslot] = best; }
    }
    __syncthreads();

    if (w2 == 0) {
        const float4 ao = s_acc[qslot][sub];
        const float Zo = s_z[qslot];
        const float mo = s_m[qslot];
        const int   bo = s_b[qslot];
        const bool takeOther = (mo > m) || (mo == m && bo < best);
        best = takeOther ? bo : best;
        Z += Zo;
        acc.x += ao.x; acc.y += ao.y; acc.z += ao.z; acc.w += ao.w;

        const float inv = 1.f / Z;
        if (half == 0) {
            float4 sv;
            sv.x = acc.x * inv; sv.y = acc.y * inv;
            sv.z = acc.z * inv; sv.w = acc.w * inv;
            s_acc[qslot][sub] = sv;       // channel-group index == sub
            if (sub == 0) out1[q] = (float)best;
        }
        // same-wave DS ordering makes the write visible to both halves below

        // final: out[dp] = sum_c s[c]*Wout[c][dp] + bout[dp] + 2*query[q][dp]
        // split-K across the two halves: half0 sums cg 0..15, half1 cg 16..31
        const int dpb = sub * 4;
        float4 r = {0.f, 0.f, 0.f, 0.f};
        if (half == 0) {
            const float4 b4 = *(const float4*)(bout + dpb);
            const float4 q4 = *(const float4*)(query + (size_t)q * EMBED + dpb);
            r.x = fmaf(2.f, q4.x, b4.x);
            r.y = fmaf(2.f, q4.y, b4.y);
            r.z = fmaf(2.f, q4.z, b4.z);
            r.w = fmaf(2.f, q4.w, b4.w);
        }
        const float4* srow = s_acc[qslot];
        const int cg0 = half * 16;
#pragma unroll 4
        for (int cg = cg0; cg < cg0 + 16; ++cg) {
            const float4 s4 = srow[cg];
            const float4 w0 = *(const float4*)(Wout + (size_t)(cg * 4 + 0) * EMBED + dpb);
            const float4 w1 = *(const float4*)(Wout + (size_t)(cg * 4 + 1) * EMBED + dpb);
            const float4 w2v = *(const float4*)(Wout + (size_t)(cg * 4 + 2) * EMBED + dpb);
            const float4 w3 = *(const float4*)(Wout + (size_t)(cg * 4 + 3) * EMBED + dpb);
            r.x = fmaf(s4.x, w0.x, r.x); r.y = fmaf(s4.x, w0.y, r.y);
            r.z = fmaf(s4.x, w0.z, r.z); r.w = fmaf(s4.x, w0.w, r.w);
            r.x = fmaf(s4.y, w1.x, r.x); r.y = fmaf(s4.y, w1.y, r.y);
            r.z = fmaf(s4.y, w1.z, r.z); r.w = fmaf(s4.y, w1.w, r.w);
            r.x = fmaf(s4.z, w2v.x, r.x); r.y = fmaf(s4.z, w2v.y, r.y);
            r.z = fmaf(s4.z, w2v.z, r.z); r.w = fmaf(s4.z, w2v.w, r.w);
            r.x = fmaf(s4.w, w3.x, r.x); r.y = fmaf(s4.w, w3.y, r.y);
            r.z = fmaf(s4.w, w3.z, r.z); r.w = fmaf(s4.w, w3.w, r.w);
        }
        // combine the two half-sums and store from half 0
        {
            const float rx = __shfl_xor(r.x, 32, 64);
            const float ry = __shfl_xor(r.y, 32, 64);
            const float rz = __shfl_xor(r.z, 32, 64);
            const float rw = __shfl_xor(r.w, 32, 64);
            r.x += rx; r.y += ry; r.z += rz; r.w += rw;
        }
        if (half == 0)
            *(float4*)(out0 + (size_t)q * EMBED + dpb) = r;
    }
}

// ---------------------------------------------------------------------------
extern "C" void kernel_launch(void* const* d_in, const int* in_sizes, int n_in,
                              void* d_out, int out_size, void* d_ws, size_t ws_size,
                              hipStream_t stream) {
    const float* query = (const float*)d_in[0];
    const float* value = (const float*)d_in[1];
    const float* refp  = (const float*)d_in[2];
    const float* Woff  = (const float*)d_in[3];
    const float* boff  = (const float*)d_in[4];
    const float* Wattn = (const float*)d_in[5];
    const float* battn = (const float*)d_in[6];
    const float* Wval  = (const float*)d_in[7];
    const float* bval  = (const float*)d_in[8];
    const float* Wout  = (const float*)d_in[9];
    const float* bout  = (const float*)d_in[10];
    const float* Wproj = (const float*)d_in[11];
    // d_in[12] = b_proj: level-constant -> cancels in softmax/argmax, unused.

    float* ws = (float*)d_ws;
    float* ws_v   = ws;                                   // NSLOT*128 padded map
    float* ws_off = ws_v + (size_t)NSLOT * EMBED;         // NQ*64
    float* ws_aw  = ws_off + (size_t)NQ * 64;             // NQ*32
    float* ws_u   = ws_aw + (size_t)NQ * 32;              // 128

    float* out0 = (float*)d_out;
    float* out1 = out0 + (size_t)NQ * EMBED;

    hipLaunchKernelGGL(k_prep, dim3(GRID_A + GRID_B + 1), dim3(256), 0, stream,
                       value, Wval, bval, query, Woff, boff, Wattn, battn,
                       Wout, Wproj, ws_v, ws_off, ws_aw, ws_u);
    hipLaunchKernelGGL(k_main, dim3(NQ / 2), dim3(256), 0, stream,
                       query, refp, ws_off, ws_aw, ws_v, ws_u, Wout, bout,
                       out0, out1);
}